// Round 10
// baseline (119.385 us; speedup 1.0000x reference)
//
#include <hip/hip_runtime.h>
#include <hip/hip_bf16.h>

typedef __bf16 bf16x8 __attribute__((ext_vector_type(8)));
typedef float f32x16 __attribute__((ext_vector_type(16)));

// ---- Gram body: G = E^T E over [nrows x 64] (optional gather), bf16 MFMA ----
// Per-wave 16-row chunks, scalar column loads feeding 32x32x16 fragments
// directly, one-chunk register prefetch. Proven 54 us/pass on item table.
template<bool GATHER>
static __device__ __forceinline__ void gram_body(
    const float* __restrict__ emb, const int* __restrict__ idx,
    int nrows, int nwaves_total, int blk,
    float* __restrict__ partial, float* __restrict__ red, int t) {
    const int lane = t & 63, wave = t >> 6;
    const int c = lane & 31, kh = lane >> 5;
    const int wid = blk * 4 + wave;
    const int step = nwaves_total * 16;

    f32x16 g00 = {}, g01 = {}, g11 = {};
    float cur0[8], cur1[8];

    int k0 = wid * 16;
    if (k0 < nrows) {
        const int kb = k0 + kh * 8;
#pragma unroll
        for (int j = 0; j < 8; ++j) {
            const size_t rb = (GATHER ? (size_t)idx[kb + j] : (size_t)(kb + j)) * 64;
            cur0[j] = emb[rb + c];
            cur1[j] = emb[rb + 32 + c];
        }
    }
    for (; k0 < nrows; k0 += step) {
        float nx0[8], nx1[8];
        const int k1 = k0 + step;
        if (k1 < nrows) {                       // prefetch next chunk
            const int kb = k1 + kh * 8;
#pragma unroll
            for (int j = 0; j < 8; ++j) {
                const size_t rb = (GATHER ? (size_t)idx[kb + j] : (size_t)(kb + j)) * 64;
                nx0[j] = emb[rb + c];
                nx1[j] = emb[rb + 32 + c];
            }
        } else {
#pragma unroll
            for (int j = 0; j < 8; ++j) { nx0[j] = 0.f; nx1[j] = 0.f; }
        }
        bf16x8 f0, f1;                          // nrows % 16 == 0 here
#pragma unroll
        for (int j = 0; j < 8; ++j) {
            f0[j] = (__bf16)cur0[j];
            f1[j] = (__bf16)cur1[j];
        }
        g00 = __builtin_amdgcn_mfma_f32_32x32x16_bf16(f0, f0, g00, 0, 0, 0);
        g01 = __builtin_amdgcn_mfma_f32_32x32x16_bf16(f0, f1, g01, 0, 0, 0);
        g11 = __builtin_amdgcn_mfma_f32_32x32x16_bf16(f1, f1, g11, 0, 0, 0);
#pragma unroll
        for (int j = 0; j < 8; ++j) { cur0[j] = nx0[j]; cur1[j] = nx1[j]; }
    }

    __syncthreads();
    for (int w = 0; w < 4; ++w) {
        if (wave == w) {
#pragma unroll
            for (int r = 0; r < 16; ++r) {
                const int cell = ((r & 3) + 8 * (r >> 2) + 4 * kh) * 32 + c;
                if (w == 0) {
                    red[cell] = g00[r]; red[1024 + cell] = g01[r]; red[2048 + cell] = g11[r];
                } else {
                    red[cell] += g00[r]; red[1024 + cell] += g01[r]; red[2048 + cell] += g11[r];
                }
            }
        }
        __syncthreads();
    }
    float* outp = partial + (size_t)blk * 3072;
    for (int i = t; i < 3072; i += 256) outp[i] = red[i];
}

// ---- fully fused heavy kernel ----------------------------------------------
// Grid = 1536 = 256 CU x 6 blocks (VGPR capped via __launch_bounds__(256,6))
// so ALL roles are co-resident from t=0 and their memory streams overlap:
//   [0,NA)            item gram   (256 MB stream, MFMA)
//   [NA,NA+NP)        pos gather  (~210 MB, mostly L3)
//   [.., +NSS)        user sumsq  (51 MB stream)
//   [.., +NU)         user gram   (gathered 1 MB)
__global__ __launch_bounds__(256, 6) void fused_kernel(
    const int* __restrict__ users, const int* __restrict__ hist,
    const float* __restrict__ user_emb, const float* __restrict__ item_emb,
    const float* __restrict__ Hw,
    int n_users, int n_items, int batch, int histL,
    int NA, int NP, int NSS, int NU,
    float* __restrict__ partA, float* __restrict__ partB,
    float* __restrict__ p1, float* __restrict__ p2, float* __restrict__ pss) {
    __shared__ float red[3072];
    const int bid = blockIdx.x, t = threadIdx.x;

    if (bid < NA) {                              // ---- item gram role
        gram_body<false>(item_emb, nullptr, n_items, NA * 4, bid,
                         partA, red, t);
    } else if (bid < NA + NP) {                  // ---- pos role
        const int pid = bid - NA;
        const int lane = t & 63, wave = t >> 6;
        const int k = lane & 15, g = lane >> 4;
        for (int w = pid * 4 + wave; w < batch; w += NP * 4) {
            const int iu = users[w];
            const float4 vu = *reinterpret_cast<const float4*>(user_emb + (size_t)iu * 64 + k * 4);
            const float4 vh = *reinterpret_cast<const float4*>(Hw + k * 4);
            const float4 uh = make_float4(vu.x * vh.x, vu.y * vh.y, vu.z * vh.z, vu.w * vh.w);
            const int* hrow = hist + (size_t)iu * histL;

            float s1 = 0.f, s2 = 0.f;
            int l = g;
            for (; l + 12 < histL; l += 16) {    // 4 groups x ILP-4
                int it[4];
#pragma unroll
                for (int u = 0; u < 4; ++u) it[u] = hrow[l + 4 * u];
                float d[4];
#pragma unroll
                for (int u = 0; u < 4; ++u) {
                    const float4 v = *reinterpret_cast<const float4*>(
                        item_emb + (size_t)it[u] * 64 + k * 4);
                    d[u] = v.x * uh.x + v.y * uh.y + v.z * uh.z + v.w * uh.w;
                }
#pragma unroll
                for (int u = 0; u < 4; ++u) {
                    float dd = d[u];
                    dd += __shfl_xor(dd, 1, 16);
                    dd += __shfl_xor(dd, 2, 16);
                    dd += __shfl_xor(dd, 4, 16);
                    dd += __shfl_xor(dd, 8, 16);
                    s1 += dd;                    // replicated x16; scaled below
                    s2 = fmaf(dd, dd, s2);
                }
            }
            for (; l < histL; l += 4) {
                const int it = hrow[l];
                const float4 v = *reinterpret_cast<const float4*>(
                    item_emb + (size_t)it * 64 + k * 4);
                float dd = v.x * uh.x + v.y * uh.y + v.z * uh.z + v.w * uh.w;
                dd += __shfl_xor(dd, 1, 16);
                dd += __shfl_xor(dd, 2, 16);
                dd += __shfl_xor(dd, 4, 16);
                dd += __shfl_xor(dd, 8, 16);
                s1 += dd;
                s2 = fmaf(dd, dd, s2);
            }
            s1 += __shfl_xor(s1, 16, 64); s1 += __shfl_xor(s1, 32, 64);
            s2 += __shfl_xor(s2, 16, 64); s2 += __shfl_xor(s2, 32, 64);
            if (lane == 0) { p1[w] = s1 * 0.0625f; p2[w] = s2 * 0.0625f; }
        }
    } else if (bid < NA + NP + NSS) {            // ---- sumsq role
        const int cid = bid - NA - NP;
        const int n4 = n_users * 16;
        float s = 0.f;
        for (int i = cid * 256 + t; i < n4; i += NSS * 256) {
            const float4 v = reinterpret_cast<const float4*>(user_emb)[i];
            s = fmaf(v.x, v.x, s); s = fmaf(v.y, v.y, s);
            s = fmaf(v.z, v.z, s); s = fmaf(v.w, v.w, s);
        }
#pragma unroll
        for (int off = 32; off >= 1; off >>= 1) s += __shfl_xor(s, off, 64);
        if ((t & 63) == 0) red[t >> 6] = s;
        __syncthreads();
        if (t == 0) pss[cid] = red[0] + red[1] + red[2] + red[3];
    } else {                                     // ---- user gram role
        gram_body<true>(user_emb, users, batch, NU * 4, bid - NA - NP - NSS,
                        partB, red, t);
    }
}

// ---- stage-1 reduce of gram partials, 8-way partial-dim split --------------
__global__ __launch_bounds__(256) void reduce_gram_kernel(
    const float* __restrict__ pa, int na,
    const float* __restrict__ pb, int nb, float* __restrict__ part2) {
    const int bid = blockIdx.x;
    const int cellblk = bid % 24, seg = bid / 24;
    const int e = cellblk * 256 + threadIdx.x;
    const float* p; int n, ee;
    if (e < 3072) { p = pa; n = na; ee = e; }
    else          { p = pb; n = nb; ee = e - 3072; }
    const int chunk = (n + 7) >> 3;
    const int b0 = seg * chunk;
    int b1 = b0 + chunk; if (b1 > n) b1 = n;
    float s[4] = {0.f, 0.f, 0.f, 0.f};
    int b = b0;
    for (; b + 4 <= b1; b += 4)
#pragma unroll
        for (int u = 0; u < 4; ++u) s[u] += p[(size_t)(b + u) * 3072 + ee];
    for (; b < b1; ++b) s[0] += p[(size_t)b * 3072 + ee];
    part2[(size_t)seg * 6144 + e] = (s[0] + s[1]) + (s[2] + s[3]);
}

// ---- finalize: 1024 threads, consumes part2 directly -----------------------
__global__ __launch_bounds__(1024) void finalize_kernel(
    const float* __restrict__ part2, const float* __restrict__ Hw,
    const float* __restrict__ p1, const float* __restrict__ p2, int npos,
    const float* __restrict__ pss, int nss, float* __restrict__ outp) {
    const int t = threadIdx.x;
    float tsum = 0.f, trace = 0.f, s1 = 0.f, s2 = 0.f, su = 0.f;
    for (int e = t; e < 3072; e += 1024) {
        float gi = 0.f, gu = 0.f;
#pragma unroll
        for (int seg = 0; seg < 8; ++seg) {
            gi += part2[(size_t)seg * 6144 + e];
            gu += part2[(size_t)seg * 6144 + 3072 + e];
        }
        const int tile = e >> 10, r = (e & 1023) >> 5, cc = e & 31;
        const int i = (tile == 2) ? r + 32 : r;
        const int j = (tile == 0) ? cc : cc + 32;
        const float w = (tile == 1) ? 2.0f : 1.0f;
        tsum += w * gi * gu * Hw[i] * Hw[j];
        if (i == j) trace += gi;
    }
    for (int e = t; e < npos; e += 1024) { s1 += p1[e]; s2 += p2[e]; }
    for (int e = t; e < nss; e += 1024) su += pss[e];
#pragma unroll
    for (int off = 32; off >= 1; off >>= 1) {
        tsum += __shfl_xor(tsum, off, 64);
        trace += __shfl_xor(trace, off, 64);
        s1 += __shfl_xor(s1, off, 64);
        s2 += __shfl_xor(s2, off, 64);
        su += __shfl_xor(su, off, 64);
    }
    __shared__ float rr[16][5];
    if ((t & 63) == 0) {
        const int w = t >> 6;
        rr[w][0] = tsum; rr[w][1] = trace; rr[w][2] = s1;
        rr[w][3] = s2;   rr[w][4] = su;
    }
    __syncthreads();
    if (t == 0) {
        float a[5] = {0.f, 0.f, 0.f, 0.f, 0.f};
        for (int w = 0; w < 16; ++w)
#pragma unroll
            for (int q = 0; q < 5; ++q) a[q] += rr[w][q];
        const float reg = 1e-4f * (sqrtf(a[4]) + sqrtf(a[1]));
        const float loss = 0.5f * a[0] + 0.5f * a[3] - 2.0f * a[2] + reg;
        outp[0] = loss; outp[1] = reg; outp[2] = reg;
    }
}

extern "C" void kernel_launch(void* const* d_in, const int* in_sizes, int n_in,
                              void* d_out, int out_size, void* d_ws, size_t ws_size,
                              hipStream_t stream) {
    const int*   users    = (const int*)d_in[0];
    const int*   hist     = (const int*)d_in[1];
    const float* user_emb = (const float*)d_in[2];
    const float* item_emb = (const float*)d_in[3];
    const float* Hw       = (const float*)d_in[4];
    float* outp = (float*)d_out;
    float* ws   = (float*)d_ws;

    const int n_users = in_sizes[2] / 64;            // 200000
    const int n_items = in_sizes[3] / 64;            // 1000000
    const int batch   = in_sizes[0];                 // 4096
    const int histL   = in_sizes[1] / n_users;       // 200

    // all-resident partition: 1536 blocks = 256 CU x 6 (VGPR-capped)
    int NA = 768;                                    // item-gram blocks
    const int NP  = 512;                             // pos blocks (2 users/wave)
    const int NSS = 192;                             // sumsq blocks
    const int NU  = 64;                              // user-gram blocks

    // ws layout (floats)
    const size_t o_p1 = 0;
    const size_t o_p2 = o_p1 + (size_t)batch;
    const size_t o_ss = o_p2 + (size_t)batch;
    const size_t o_part2 = o_ss + NSS;
    const size_t o_part = o_part2 + 8 * 6144;
    long availf = (long)(ws_size / 4) - (long)o_part - (long)NU * 3072;
    if ((long)NA * 3072 > availf) {
        NA = (int)(availf / 3072);
        if (NA < 8) NA = 8;
    }
    float* partA = ws + o_part;
    float* partB = partA + (size_t)NA * 3072;

    fused_kernel<<<NA + NP + NSS + NU, 256, 0, stream>>>(
        users, hist, user_emb, item_emb, Hw,
        n_users, n_items, batch, histL,
        NA, NP, NSS, NU,
        partA, partB, ws + o_p1, ws + o_p2, ws + o_ss);
    reduce_gram_kernel<<<24 * 8, 256, 0, stream>>>(
        partA, NA, partB, NU, ws + o_part2);
    finalize_kernel<<<1, 1024, 0, stream>>>(
        ws + o_part2, Hw, ws + o_p1, ws + o_p2, batch,
        ws + o_ss, NSS, outp);
}

// Round 11
// 110.206 us; speedup vs baseline: 1.0833x; 1.0833x over previous
//
#include <hip/hip_runtime.h>
#include <hip/hip_bf16.h>

typedef __bf16 bf16x8 __attribute__((ext_vector_type(8)));
typedef float f32x16 __attribute__((ext_vector_type(16)));

// ---- Gram body: G = E^T E over [nrows x 64] (optional gather), bf16 MFMA ----
// Per-wave 16-row chunks, scalar column loads feeding 32x32x16 fragments
// directly, one-chunk register prefetch. Needs ~88 regs (48 acc + staging);
// launch_bounds must keep the VGPR cap >= that (4 blocks/CU -> cap 128).
template<bool GATHER>
static __device__ __forceinline__ void gram_body(
    const float* __restrict__ emb, const int* __restrict__ idx,
    int nrows, int nwaves_total, int blk,
    float* __restrict__ partial, float* __restrict__ red, int t) {
    const int lane = t & 63, wave = t >> 6;
    const int c = lane & 31, kh = lane >> 5;
    const int wid = blk * 4 + wave;
    const int step = nwaves_total * 16;

    f32x16 g00 = {}, g01 = {}, g11 = {};
    float cur0[8], cur1[8];

    int k0 = wid * 16;
    if (k0 < nrows) {
        const int kb = k0 + kh * 8;
#pragma unroll
        for (int j = 0; j < 8; ++j) {
            const size_t rb = (GATHER ? (size_t)idx[kb + j] : (size_t)(kb + j)) * 64;
            cur0[j] = emb[rb + c];
            cur1[j] = emb[rb + 32 + c];
        }
    }
    for (; k0 < nrows; k0 += step) {
        float nx0[8], nx1[8];
        const int k1 = k0 + step;
        if (k1 < nrows) {                       // prefetch next chunk
            const int kb = k1 + kh * 8;
#pragma unroll
            for (int j = 0; j < 8; ++j) {
                const size_t rb = (GATHER ? (size_t)idx[kb + j] : (size_t)(kb + j)) * 64;
                nx0[j] = emb[rb + c];
                nx1[j] = emb[rb + 32 + c];
            }
        } else {
#pragma unroll
            for (int j = 0; j < 8; ++j) { nx0[j] = 0.f; nx1[j] = 0.f; }
        }
        bf16x8 f0, f1;                          // nrows % 16 == 0 here
#pragma unroll
        for (int j = 0; j < 8; ++j) {
            f0[j] = (__bf16)cur0[j];
            f1[j] = (__bf16)cur1[j];
        }
        g00 = __builtin_amdgcn_mfma_f32_32x32x16_bf16(f0, f0, g00, 0, 0, 0);
        g01 = __builtin_amdgcn_mfma_f32_32x32x16_bf16(f0, f1, g01, 0, 0, 0);
        g11 = __builtin_amdgcn_mfma_f32_32x32x16_bf16(f1, f1, g11, 0, 0, 0);
#pragma unroll
        for (int j = 0; j < 8; ++j) { cur0[j] = nx0[j]; cur1[j] = nx1[j]; }
    }

    __syncthreads();
    for (int w = 0; w < 4; ++w) {
        if (wave == w) {
#pragma unroll
            for (int r = 0; r < 16; ++r) {
                const int cell = ((r & 3) + 8 * (r >> 2) + 4 * kh) * 32 + c;
                if (w == 0) {
                    red[cell] = g00[r]; red[1024 + cell] = g01[r]; red[2048 + cell] = g11[r];
                } else {
                    red[cell] += g00[r]; red[1024 + cell] += g01[r]; red[2048 + cell] += g11[r];
                }
            }
        }
        __syncthreads();
    }
    float* outp = partial + (size_t)blk * 3072;
    for (int i = t; i < 3072; i += 256) outp[i] = red[i];
}

// ---- fully fused heavy kernel ----------------------------------------------
// Grid = 1024 = 256 CU x 4 blocks -> all roles co-resident from t=0, no VGPR
// spill (cap 128 >= ~88 needed by gram).
__global__ __launch_bounds__(256, 4) void fused_kernel(
    const int* __restrict__ users, const int* __restrict__ hist,
    const float* __restrict__ user_emb, const float* __restrict__ item_emb,
    const float* __restrict__ Hw,
    int n_users, int n_items, int batch, int histL,
    int NA, int NP, int NSS, int NU,
    float* __restrict__ partA, float* __restrict__ partB,
    float* __restrict__ p1, float* __restrict__ p2, float* __restrict__ pss) {
    __shared__ float red[3072];
    const int bid = blockIdx.x, t = threadIdx.x;

    if (bid < NA) {                              // ---- item gram role
        gram_body<false>(item_emb, nullptr, n_items, NA * 4, bid,
                         partA, red, t);
    } else if (bid < NA + NP) {                  // ---- pos role (grid-stride)
        const int pid = bid - NA;
        const int lane = t & 63, wave = t >> 6;
        const int k = lane & 15, g = lane >> 4;
        for (int w = pid * 4 + wave; w < batch; w += NP * 4) {
            const int iu = users[w];
            const float4 vu = *reinterpret_cast<const float4*>(user_emb + (size_t)iu * 64 + k * 4);
            const float4 vh = *reinterpret_cast<const float4*>(Hw + k * 4);
            const float4 uh = make_float4(vu.x * vh.x, vu.y * vh.y, vu.z * vh.z, vu.w * vh.w);
            const int* hrow = hist + (size_t)iu * histL;

            float s1 = 0.f, s2 = 0.f;
            int l = g;
            for (; l + 12 < histL; l += 16) {    // 4 groups x ILP-4
                int it[4];
#pragma unroll
                for (int u = 0; u < 4; ++u) it[u] = hrow[l + 4 * u];
                float d[4];
#pragma unroll
                for (int u = 0; u < 4; ++u) {
                    const float4 v = *reinterpret_cast<const float4*>(
                        item_emb + (size_t)it[u] * 64 + k * 4);
                    d[u] = v.x * uh.x + v.y * uh.y + v.z * uh.z + v.w * uh.w;
                }
#pragma unroll
                for (int u = 0; u < 4; ++u) {
                    float dd = d[u];
                    dd += __shfl_xor(dd, 1, 16);
                    dd += __shfl_xor(dd, 2, 16);
                    dd += __shfl_xor(dd, 4, 16);
                    dd += __shfl_xor(dd, 8, 16);
                    s1 += dd;                    // replicated x16; scaled below
                    s2 = fmaf(dd, dd, s2);
                }
            }
            for (; l < histL; l += 4) {
                const int it = hrow[l];
                const float4 v = *reinterpret_cast<const float4*>(
                    item_emb + (size_t)it * 64 + k * 4);
                float dd = v.x * uh.x + v.y * uh.y + v.z * uh.z + v.w * uh.w;
                dd += __shfl_xor(dd, 1, 16);
                dd += __shfl_xor(dd, 2, 16);
                dd += __shfl_xor(dd, 4, 16);
                dd += __shfl_xor(dd, 8, 16);
                s1 += dd;
                s2 = fmaf(dd, dd, s2);
            }
            s1 += __shfl_xor(s1, 16, 64); s1 += __shfl_xor(s1, 32, 64);
            s2 += __shfl_xor(s2, 16, 64); s2 += __shfl_xor(s2, 32, 64);
            if (lane == 0) { p1[w] = s1 * 0.0625f; p2[w] = s2 * 0.0625f; }
        }
    } else if (bid < NA + NP + NSS) {            // ---- sumsq role
        const int cid = bid - NA - NP;
        const int n4 = n_users * 16;
        float s = 0.f;
        for (int i = cid * 256 + t; i < n4; i += NSS * 256) {
            const float4 v = reinterpret_cast<const float4*>(user_emb)[i];
            s = fmaf(v.x, v.x, s); s = fmaf(v.y, v.y, s);
            s = fmaf(v.z, v.z, s); s = fmaf(v.w, v.w, s);
        }
#pragma unroll
        for (int off = 32; off >= 1; off >>= 1) s += __shfl_xor(s, off, 64);
        if ((t & 63) == 0) red[t >> 6] = s;
        __syncthreads();
        if (t == 0) pss[cid] = red[0] + red[1] + red[2] + red[3];
    } else {                                     // ---- user gram role
        gram_body<true>(user_emb, users, batch, NU * 4, bid - NA - NP - NSS,
                        partB, red, t);
    }
}

// ---- stage-1 reduce of gram partials, 8-way partial-dim split --------------
__global__ __launch_bounds__(256) void reduce_gram_kernel(
    const float* __restrict__ pa, int na,
    const float* __restrict__ pb, int nb, float* __restrict__ part2) {
    const int bid = blockIdx.x;
    const int cellblk = bid % 24, seg = bid / 24;
    const int e = cellblk * 256 + threadIdx.x;
    const float* p; int n, ee;
    if (e < 3072) { p = pa; n = na; ee = e; }
    else          { p = pb; n = nb; ee = e - 3072; }
    const int chunk = (n + 7) >> 3;
    const int b0 = seg * chunk;
    int b1 = b0 + chunk; if (b1 > n) b1 = n;
    float s[4] = {0.f, 0.f, 0.f, 0.f};
    int b = b0;
    for (; b + 4 <= b1; b += 4)
#pragma unroll
        for (int u = 0; u < 4; ++u) s[u] += p[(size_t)(b + u) * 3072 + ee];
    for (; b < b1; ++b) s[0] += p[(size_t)b * 3072 + ee];
    part2[(size_t)seg * 6144 + e] = (s[0] + s[1]) + (s[2] + s[3]);
}

// ---- finalize: 1024 threads, consumes part2 directly -----------------------
__global__ __launch_bounds__(1024) void finalize_kernel(
    const float* __restrict__ part2, const float* __restrict__ Hw,
    const float* __restrict__ p1, const float* __restrict__ p2, int npos,
    const float* __restrict__ pss, int nss, float* __restrict__ outp) {
    const int t = threadIdx.x;
    float tsum = 0.f, trace = 0.f, s1 = 0.f, s2 = 0.f, su = 0.f;
    for (int e = t; e < 3072; e += 1024) {
        float gi = 0.f, gu = 0.f;
#pragma unroll
        for (int seg = 0; seg < 8; ++seg) {
            gi += part2[(size_t)seg * 6144 + e];
            gu += part2[(size_t)seg * 6144 + 3072 + e];
        }
        const int tile = e >> 10, r = (e & 1023) >> 5, cc = e & 31;
        const int i = (tile == 2) ? r + 32 : r;
        const int j = (tile == 0) ? cc : cc + 32;
        const float w = (tile == 1) ? 2.0f : 1.0f;
        tsum += w * gi * gu * Hw[i] * Hw[j];
        if (i == j) trace += gi;
    }
    for (int e = t; e < npos; e += 1024) { s1 += p1[e]; s2 += p2[e]; }
    for (int e = t; e < nss; e += 1024) su += pss[e];
#pragma unroll
    for (int off = 32; off >= 1; off >>= 1) {
        tsum += __shfl_xor(tsum, off, 64);
        trace += __shfl_xor(trace, off, 64);
        s1 += __shfl_xor(s1, off, 64);
        s2 += __shfl_xor(s2, off, 64);
        su += __shfl_xor(su, off, 64);
    }
    __shared__ float rr[16][5];
    if ((t & 63) == 0) {
        const int w = t >> 6;
        rr[w][0] = tsum; rr[w][1] = trace; rr[w][2] = s1;
        rr[w][3] = s2;   rr[w][4] = su;
    }
    __syncthreads();
    if (t == 0) {
        float a[5] = {0.f, 0.f, 0.f, 0.f, 0.f};
        for (int w = 0; w < 16; ++w)
#pragma unroll
            for (int q = 0; q < 5; ++q) a[q] += rr[w][q];
        const float reg = 1e-4f * (sqrtf(a[4]) + sqrtf(a[1]));
        const float loss = 0.5f * a[0] + 0.5f * a[3] - 2.0f * a[2] + reg;
        outp[0] = loss; outp[1] = reg; outp[2] = reg;
    }
}

extern "C" void kernel_launch(void* const* d_in, const int* in_sizes, int n_in,
                              void* d_out, int out_size, void* d_ws, size_t ws_size,
                              hipStream_t stream) {
    const int*   users    = (const int*)d_in[0];
    const int*   hist     = (const int*)d_in[1];
    const float* user_emb = (const float*)d_in[2];
    const float* item_emb = (const float*)d_in[3];
    const float* Hw       = (const float*)d_in[4];
    float* outp = (float*)d_out;
    float* ws   = (float*)d_ws;

    const int n_users = in_sizes[2] / 64;            // 200000
    const int n_items = in_sizes[3] / 64;            // 1000000
    const int batch   = in_sizes[0];                 // 4096
    const int histL   = in_sizes[1] / n_users;       // 200

    // all-resident partition: 1024 blocks = 256 CU x 4 (no VGPR spill)
    int NA = 512;                                    // item-gram blocks
    const int NP  = 384;                             // pos blocks
    const int NSS = 96;                              // sumsq blocks
    const int NU  = 32;                              // user-gram blocks

    // ws layout (floats)
    const size_t o_p1 = 0;
    const size_t o_p2 = o_p1 + (size_t)batch;
    const size_t o_ss = o_p2 + (size_t)batch;
    const size_t o_part2 = o_ss + NSS;
    const size_t o_part = o_part2 + 8 * 6144;
    long availf = (long)(ws_size / 4) - (long)o_part - (long)NU * 3072;
    if ((long)NA * 3072 > availf) {
        NA = (int)(availf / 3072);
        if (NA < 8) NA = 8;
    }
    float* partA = ws + o_part;
    float* partB = partA + (size_t)NA * 3072;

    fused_kernel<<<NA + NP + NSS + NU, 256, 0, stream>>>(
        users, hist, user_emb, item_emb, Hw,
        n_users, n_items, batch, histL,
        NA, NP, NSS, NU,
        partA, partB, ws + o_p1, ws + o_p2, ws + o_ss);
    reduce_gram_kernel<<<24 * 8, 256, 0, stream>>>(
        partA, NA, partB, NU, ws + o_part2);
    finalize_kernel<<<1, 1024, 0, stream>>>(
        ws + o_part2, Hw, ws + o_p1, ws + o_p2, batch,
        ws + o_ss, NSS, outp);
}